// Round 17
// baseline (17.485 us; speedup 1.0000x reference)
//
#include <hip/hip_runtime.h>
#include <hip/hip_fp16.h>

// CropRoi: 3D adaptive max-pool over per-proposal crop boxes.
// f:        [B=4, C=64, 24, 24, 24] f32
// proposals:[N, 8] f32 = [b, score, cx, cy, cz, sx, sy, sz]
// out:      [N, C, 7, 7, 7] f32
//
// K1 (r15, proven): transpose+fp16 f -> ft[b][s][c]; 1728 blocks.
// K2 (r16): union-load separable pool, grid (N,7,2); grid.z = CHANNEL half
//   (octets 0-3 / 4-7), so each block z-pools its full y-range ONCE:
//   Phase A : unit (y<L1, x<L2, c8l<4) — no padded units; ez-loop (uniform)
//             global loads 64B-contiguous -> T[y][x][c8l] (z-pooled slab).
//   Phase A2: y-pool from LDS T -> P[j][x][c8l] (<=3 ds_read_b128 each);
//             the y-overlap between adjacent j now costs LDS, not HBM.
//   Phase B : x-pool P -> obuf f32 [49][33] (conflict-free pitch).
//   Phase C : coalesced 49-run write-out for 32 channels.
//   Removes the 1.65x y read-amplification of r15 (K2 read ~27 -> ~16.5 MB).
//
// History: r9 grid.sync / r12 pc-flag 100-155us (cross-XCD sync dead);
// r13 direct 52.8us (serial LDS chains dead); r10 672-block (low TLP) dead;
// r8 predication -3.1us; r15 occupancy fixes -1.3us.
// Precision: fp16 RTN on ~N(0,1); absmax 0.03125 << 0.099.

#define SS 7
#define CC 64
#define DP 24
#define DP2 (DP*DP)        // 576
#define VOL (DP*DP*DP)     // 13824
#define INV_SCALE 0.25f
#define NEGINF2 0xFC00FC00u

static __device__ __forceinline__ unsigned pkmax(unsigned a, unsigned b) {
    unsigned r;
    asm("v_pk_max_f16 %0, %1, %2" : "=v"(r) : "v"(a), "v"(b));
    return r;
}
static __device__ __forceinline__ uint4 pkmax4(uint4 a, uint4 b) {
    uint4 r;
    r.x = pkmax(a.x, b.x); r.y = pkmax(a.y, b.y);
    r.z = pkmax(a.z, b.z); r.w = pkmax(a.w, b.w);
    return r;
}

// ---------------- kernel 1: channel-last transpose to fp16 (r15 body) ------
__global__ __launch_bounds__(256) void transpose_cl(
    const float* __restrict__ f,   // [B][CC][VOL] f32
    uint4* __restrict__ ft4)       // [B][VOL][CC/8]
{
    __shared__ float tile[64][33];     // 8448 B
    const int b  = blockIdx.y;
    const int s0 = blockIdx.x * 32;
    const int t  = threadIdx.x;
    const int x4 = (t & 7) * 4;        // spatial quad within tile
    const int rr = t >> 3;             // 0..31
    #pragma unroll
    for (int it = 0; it < 2; ++it) {
        const int r = it * 32 + rr;    // channel
        const float4 v = *(const float4*)&f[(size_t)(b * CC + r) * VOL + s0 + x4];
        tile[r][x4 + 0] = v.x; tile[r][x4 + 1] = v.y;
        tile[r][x4 + 2] = v.z; tile[r][x4 + 3] = v.w;
    }
    __syncthreads();
    const int s  = t >> 3;             // spatial within tile (0..31)
    const int c8 = (t & 7) * 8;        // channel octet
    __half h[8];
    #pragma unroll
    for (int u = 0; u < 8; ++u)
        h[u] = __float2half(tile[c8 + u][s]);   // 2-way bank alias: free
    ft4[((size_t)b * VOL + s0 + s) * (CC / 8) + (c8 >> 3)] = *(uint4*)h;
}

// ---------------- kernel 2: union-load separable pool, channel-half split ---
__global__ __launch_bounds__(256) void croproi_union(
    const __half* __restrict__ ft,    // [B][VOL][CC] fp16
    const float* __restrict__ props,  // [N][8]
    float* __restrict__ out)          // [N][CC][343] f32
{
    __shared__ uint4 T[13 * 13 * 4];  // z-pooled slab [y][x][c8l]  10,816 B
    __shared__ uint4 P[7 * 13 * 4];   // zy-pooled     [j][x][c8l]   5,824 B
    __shared__ float obuf[49 * 33];   //                             6,468 B
    const int n  = blockIdx.x;
    const int i  = blockIdx.y;        // z-bin slice
    const int zc = blockIdx.z;        // channel half: octets zc*4 .. zc*4+3
    const int t  = threadIdx.x;

    // ---- box decode (wave-uniform -> SGPR) ----
    const float* p = props + (size_t)n * 8;
    int b = (int)p[0];
    int lo0, lo1, lo2, L0, L1, L2;
    {
        float c0f = p[2] - 0.5f * p[5];
        float c1f = c0f + p[5];
        int lo = (int)floorf(c0f * INV_SCALE); if (lo < 0) lo = 0;
        int hi = (int)ceilf (c1f * INV_SCALE); if (hi > DP) hi = DP;
        lo0 = lo; L0 = hi - lo;

        c0f = p[3] - 0.5f * p[6];
        c1f = c0f + p[6];
        lo = (int)floorf(c0f * INV_SCALE); if (lo < 0) lo = 0;
        hi = (int)ceilf (c1f * INV_SCALE); if (hi > DP) hi = DP;
        lo1 = lo; L1 = hi - lo;

        c0f = p[4] - 0.5f * p[7];
        c1f = c0f + p[7];
        lo = (int)floorf(c0f * INV_SCALE); if (lo < 0) lo = 0;
        hi = (int)ceilf (c1f * INV_SCALE); if (hi > DP) hi = DP;
        lo2 = lo; L2 = hi - lo;
    }
    b   = __builtin_amdgcn_readfirstlane(b);
    lo0 = __builtin_amdgcn_readfirstlane(lo0);
    lo1 = __builtin_amdgcn_readfirstlane(lo1);
    lo2 = __builtin_amdgcn_readfirstlane(lo2);
    L0  = __builtin_amdgcn_readfirstlane(L0);
    L1  = __builtin_amdgcn_readfirstlane(L1);
    L2  = __builtin_amdgcn_readfirstlane(L2);

    const int zs = (i * L0) / SS;
    const int ez = ((i + 1) * L0 + 6) / SS - zs;        // 1..3 (uniform)

    // base at (b, lo0+zs, lo1, lo2), this block's first octet, uint4 units
    const uint4* base0 = (const uint4*)ft
        + ((size_t)b * VOL + (size_t)(lo0 + zs) * DP2
           + (size_t)lo1 * DP + lo2) * 8 + zc * 4;

    // ---- phase A: z-pool union slab -> T[y][x][c8l] (all units real) ----
    const int unitsA = L1 * L2 * 4;             // <= 676
    for (int u = t; u < unitsA; u += 256) {
        const int c8l = u & 3;
        const int v   = u >> 2;                 // y*L2 + x
        const int y   = v / L2;                 // runtime div (uniform divisor)
        const int x   = v - y * L2;

        const uint4* bp = base0 + (y * DP + x) * 8 + c8l;
        uint4 m = bp[0];
        if (ez > 1) m = pkmax4(m, bp[DP2 * 8]);
        if (ez > 2) m = pkmax4(m, bp[2 * DP2 * 8]);
        T[(y * 13 + x) * 4 + c8l] = m;
    }
    __syncthreads();

    // ---- phase A2: y-pool from LDS T -> P[j][x][c8l] ----
    for (int u = t; u < 7 * 13 * 4; u += 256) { // 364 units
        const int c8l = u & 3;
        const int v   = u >> 2;                 // j*13 + x
        const int j   = v / 13;                 // const-divisor magic
        const int x   = v - j * 13;
        if (x < L2) {
            const int ys = (j * L1) / SS;
            const int ey = ((j + 1) * L1 + 6) / SS - ys;     // 1..3
            const uint4* tp = &T[(ys * 13 + x) * 4 + c8l];
            uint4 m = tp[0];
            if (ey > 1) m = pkmax4(m, tp[13 * 4]);
            if (ey > 2) m = pkmax4(m, tp[2 * 13 * 4]);
            P[(j * 13 + x) * 4 + c8l] = m;
        }
    }
    __syncthreads();

    // ---- phase B: x-pool P -> obuf f32 [49][33] ----
    if (t < 196) {
        const int jk  = t >> 2;
        const int c8l = t & 3;
        const int j   = jk / SS;                // const-divisor magic
        const int k   = jk - j * SS;
        const int xs  = (k * L2) / SS;
        const int ex  = ((k + 1) * L2 + 6) / SS - xs;    // 1..3
        const uint4* pp = &P[(j * 13 + xs) * 4 + c8l];
        uint4 m = pp[0];
        if (ex > 1) m = pkmax4(m, pp[4]);
        if (ex > 2) m = pkmax4(m, pp[8]);

        float* o = &obuf[jk * 33 + c8l * 8];
        __half2 h;
        h = *(const __half2*)&m.x; o[0] = __half2float(h.x); o[1] = __half2float(h.y);
        h = *(const __half2*)&m.y; o[2] = __half2float(h.x); o[3] = __half2float(h.y);
        h = *(const __half2*)&m.z; o[4] = __half2float(h.x); o[5] = __half2float(h.y);
        h = *(const __half2*)&m.w; o[6] = __half2float(h.x); o[7] = __half2float(h.y);
    }
    __syncthreads();

    // ---- phase C: coalesced write-out (49-float runs, 32 channels) ----
    float* op = out + ((size_t)n * CC + zc * 32) * (SS * SS * SS) + (size_t)i * 49;
    for (int idx = t; idx < 32 * 49; idx += 256) {
        const int c = idx / 49;                 // const-divisor magic
        const int q = idx - c * 49;
        op[(size_t)c * 343 + q] = obuf[q * 33 + c];   // stride 33: conflict-free
    }
}

// ---------------- fallback: round-0 thread-per-bin (proven) --------
__global__ __launch_bounds__(256) void croproi_fallback(
    const float* __restrict__ f, const float* __restrict__ props,
    float* __restrict__ out, int total)
{
    int tid = blockIdx.x * blockDim.x + threadIdx.x;
    if (tid >= total) return;
    int k = tid % SS;
    int t = tid / SS;
    int j = t % SS; t /= SS;
    int i = t % SS; t /= SS;
    int c = t % CC;
    int n = t / CC;
    const float* p = props + n * 8;
    int b = (int)p[0];
    int lo0, lo1, lo2, L0, L1, L2;
    {
        float c0f = p[2] - 0.5f * p[5]; float c1f = c0f + p[5];
        int lo = (int)floorf(c0f * INV_SCALE); if (lo < 0) lo = 0;
        int hi = (int)ceilf (c1f * INV_SCALE); if (hi > DP) hi = DP;
        lo0 = lo; L0 = hi - lo;
        c0f = p[3] - 0.5f * p[6]; c1f = c0f + p[6];
        lo = (int)floorf(c0f * INV_SCALE); if (lo < 0) lo = 0;
        hi = (int)ceilf (c1f * INV_SCALE); if (hi > DP) hi = DP;
        lo1 = lo; L1 = hi - lo;
        c0f = p[4] - 0.5f * p[7]; c1f = c0f + p[7];
        lo = (int)floorf(c0f * INV_SCALE); if (lo < 0) lo = 0;
        hi = (int)ceilf (c1f * INV_SCALE); if (hi > DP) hi = DP;
        lo2 = lo; L2 = hi - lo;
    }
    int zs = lo0 + (i * L0) / SS, ze = lo0 + ((i + 1) * L0 + SS - 1) / SS;
    int ys = lo1 + (j * L1) / SS, ye = lo1 + ((j + 1) * L1 + SS - 1) / SS;
    int xs = lo2 + (k * L2) / SS, xe = lo2 + ((k + 1) * L2 + SS - 1) / SS;
    const float* fb = f + (size_t)(b * CC + c) * VOL;
    float m = -INFINITY;
    for (int z = zs; z < ze; ++z)
        for (int y = ys; y < ye; ++y) {
            const float* row = fb + (z * DP + y) * DP;
            for (int x = xs; x < xe; ++x) m = fmaxf(m, row[x]);
        }
    out[tid] = m;
}

extern "C" void kernel_launch(void* const* d_in, const int* in_sizes, int n_in,
                              void* d_out, int out_size, void* d_ws, size_t ws_size,
                              hipStream_t stream) {
    const float* f     = (const float*)d_in[0];
    const float* props = (const float*)d_in[2];
    float* out = (float*)d_out;

    const int B = in_sizes[0] / (CC * VOL);   // 4
    const int N = in_sizes[2] / 8;            // 96

    const size_t ft_bytes = (size_t)B * VOL * CC * sizeof(__half);
    if (ws_size >= ft_bytes) {
        __half* ft = (__half*)d_ws;
        dim3 g1(VOL / 32, B);                 // 432 x 4 = 1728 blocks
        transpose_cl<<<g1, 256, 0, stream>>>(f, (uint4*)ft);
        dim3 g2(N, SS, 2);                    // 96 x 7 x 2 = 1344 blocks
        croproi_union<<<g2, 256, 0, stream>>>(ft, props, out);
    } else {
        int total = N * CC * SS * SS * SS;
        croproi_fallback<<<(total + 255) / 256, 256, 0, stream>>>(f, props, out, total);
    }
}